// Round 8
// baseline (683.271 us; speedup 1.0000x reference)
//
#include <hip/hip_runtime.h>
#include <cmath>

using short8 = __attribute__((ext_vector_type(8))) short;
using f32x4  = __attribute__((ext_vector_type(4))) float;

#define DELTA 0.02f
#define CAP   16

// d_ws layout (floats):
//   [0      .. 1024)   ee[k] = numpy-pairwise sum of E[k][:]^2  (f32)
//   [1024   .. 2048)   counts[k]
//   [2048   .. 67584)  dw[k][d]  (1024*64)
//   [67584]            mse accumulator
//   [69632  .. 102400) E_bf swizzled: A-fragment order (chunk-major, lane-contig)
//
// d_out layout (floats, reference return order):
//   [0 .. 4194304) quant | [4194304] loss | [4194305 .. 4259841) idx |
//   [4259841 .. 4325377) new_embedding | [4325377..4326401) new_cs |
//   [4326401 .. 4391937) new_ema_w

__device__ __forceinline__ unsigned short f2bf(float f) {
    unsigned u = __builtin_bit_cast(unsigned, f);
    return (unsigned short)((u + 0x7FFFu + ((u >> 16) & 1u)) >> 16);
}

__global__ __launch_bounds__(256) void vq_init_kernel(const float* __restrict__ E,
                                                      float* __restrict__ ws) {
    #pragma clang fp contract(off)
    int g = blockIdx.x * 256 + threadIdx.x;        // 256 blocks -> g in [0,65536)
    ws[2048 + g] = 0.0f;                           // zero dw
    {   // E -> bf16, swizzled into MFMA A-frag order:
        // code c, dim d: kh=d>>5, kq=(d&31)>>3, j=d&7, lane=(kq<<4)|(c&15)
        // flat = (((c>>4)*2 + kh)*64 + lane)*8 + j
        int c = g >> 6, d = g & 63;
        int kh = d >> 5, kq = (d & 31) >> 3, j = d & 7;
        int lane = (kq << 4) | (c & 15);
        int flat = (((c >> 4) * 2 + kh) * 64 + lane) * 8 + j;
        ((unsigned short*)(ws + 69632))[flat] = f2bf(E[g]);
    }
    if (g < 1024) {
        ws[1024 + g] = 0.0f;                       // zero counts
        const float* e = E + g * 64;
        float r[8];                                // numpy pairwise, n=64
        #pragma unroll
        for (int j = 0; j < 8; ++j) r[j] = e[j] * e[j];
        #pragma unroll
        for (int t = 1; t < 8; ++t)
            #pragma unroll
            for (int j = 0; j < 8; ++j) {
                float sq = e[8 * t + j] * e[8 * t + j];
                r[j] = r[j] + sq;
            }
        ws[g] = ((r[0] + r[1]) + (r[2] + r[3])) + ((r[4] + r[5]) + (r[6] + r[7]));
    }
    if (g == 0) ws[67584] = 0.0f;                  // mse
}

// Streaming exact dot: d-ascending single FMA chain (bit-exact), ~12 live regs.
__device__ __forceinline__ float chain_m(const float* __restrict__ erow,
                                         const float* __restrict__ xrow) {
    #pragma clang fp contract(off)
    float m = 0.0f;
    #pragma unroll
    for (int k = 0; k < 16; ++k) {
        float4 e  = *(const float4*)(erow + 4 * k);
        float4 xv = *(const float4*)(xrow + 4 * k);
        m = fmaf(xv.x, e.x, m);
        m = fmaf(xv.y, e.y, m);
        m = fmaf(xv.z, e.z, m);
        m = fmaf(xv.w, e.w, m);
    }
    return m;
}

// bf16-pack 8 consecutive floats; returns by value (registers, not scratch).
__device__ __forceinline__ short8 pack_bf8(const float* __restrict__ xr) {
    float f0 = xr[0], f1 = xr[1], f2 = xr[2], f3 = xr[3];
    float f4 = xr[4], f5 = xr[5], f6 = xr[6], f7 = xr[7];
    short8 r;
    r[0] = (short)f2bf(f0); r[1] = (short)f2bf(f1);
    r[2] = (short)f2bf(f2); r[3] = (short)f2bf(f3);
    r[4] = (short)f2bf(f4); r[5] = (short)f2bf(f5);
    r[6] = (short)f2bf(f6); r[7] = (short)f2bf(f7);
    return r;
}

#define MFMA16(a, b, c) __builtin_amdgcn_mfma_f32_16x16x32_bf16(a, b, c, 0, 0, 0)

__global__ __launch_bounds__(256, 2) void vq_main_kernel(
    const float* __restrict__ x, const float* __restrict__ E,
    const float* __restrict__ R, float* __restrict__ ws, float* __restrict__ out)
{
    #pragma clang fp contract(off)
    __shared__ float s_xr[64][68];     // x_rot f32, exact reference bits
    __shared__ float s_q [64][68];     // phase A: s_cand/s_wbest/s_thr; phase B: quant rows
    __shared__ float s_xx[64];
    __shared__ int   s_idx[64];
    __shared__ int   s_cnt[64];
    __shared__ float s_red[8];

    int*   s_cand  = (int*)&s_q[0][0];            // [64][CAP] ints   (floats 0..1023)
    float* s_wbest = &s_q[0][0] + 1024;           // [4][64]          (floats 1024..1279)
    float* s_thr   = &s_q[0][0] + 1280;           // [64]             (floats 1280..1343)

    const int tid  = threadIdx.x;
    const int brow = blockIdx.x;       // b*64 + h
    const int b = brow >> 6, h = brow & 63;

    const float* ee_g  = ws;
    float* counts  = ws + 1024;
    float* dw      = ws + 2048;
    float* mse_acc = ws + 67584;
    const unsigned short* ebf = (const unsigned short*)(ws + 69632);
    float* out_q   = out;
    float* out_idx = out + 4194305;

    const size_t xbase = (size_t)b * 262144 + (size_t)h * 64;

    // ---- phase 1: rotate from global, exact d-ascending f32 FMA chain ----
    {
        const int tc = tid >> 4, cg = tid & 15;    // tokens 4tc..4tc+3, j 4cg..4cg+3
        float acc[4][4] = {};
        const float* xp = x + xbase + 4 * tc;
        const float* rp = R + 4 * cg;
        #pragma unroll 8
        for (int d = 0; d < 64; ++d) {
            float4 xv = *(const float4*)(xp + (size_t)d * 4096);
            float4 rv = *(const float4*)(rp + d * 64);
            float xa[4] = {xv.x, xv.y, xv.z, xv.w};
            float ra[4] = {rv.x, rv.y, rv.z, rv.w};
            #pragma unroll
            for (int i = 0; i < 4; ++i)
                #pragma unroll
                for (int jj = 0; jj < 4; ++jj)
                    acc[i][jj] = fmaf(xa[i], ra[jj], acc[i][jj]);
        }
        #pragma unroll
        for (int i = 0; i < 4; ++i)
            *(float4*)&s_xr[4 * tc + i][4 * cg] =
                make_float4(acc[i][0], acc[i][1], acc[i][2], acc[i][3]);
    }
    __syncthreads();

    // ---- phase 2: xx (numpy pairwise, exact) + counters ----
    if (tid < 64) {
        const int w = tid;
        float r[8];
        #pragma unroll
        for (int j = 0; j < 8; ++j) { float u = s_xr[w][j]; r[j] = u * u; }
        #pragma unroll
        for (int t = 1; t < 8; ++t)
            #pragma unroll
            for (int j = 0; j < 8; ++j) {
                float u = s_xr[w][8 * t + j];
                float sq = u * u;
                r[j] = r[j] + sq;
            }
        s_xx[w] = ((r[0] + r[1]) + (r[2] + r[3])) + ((r[4] + r[5]) + (r[6] + r[7]));
        s_cnt[w] = 0;
    }
    __syncthreads();

    // ---- phase 3: named b-frags (bf16) for the 4 token groups ----
    const int lane = tid & 63, wv = tid >> 6;
    const int col  = lane & 15;
    const int kb   = (lane >> 4) * 8;
    const short8 b0_0 = pack_bf8(&s_xr[ 0 + col][kb]);
    const short8 b1_0 = pack_bf8(&s_xr[ 0 + col][kb + 32]);
    const short8 b0_1 = pack_bf8(&s_xr[16 + col][kb]);
    const short8 b1_1 = pack_bf8(&s_xr[16 + col][kb + 32]);
    const short8 b0_2 = pack_bf8(&s_xr[32 + col][kb]);
    const short8 b1_2 = pack_bf8(&s_xr[32 + col][kb + 32]);
    const short8 b0_3 = pack_bf8(&s_xr[48 + col][kb]);
    const short8 b1_3 = pack_bf8(&s_xr[48 + col][kb + 32]);

    // ---- phase 4: screen pass 1 — per-token max over this wave's 256 codes ----
    float best_0 = -1.0e30f, best_1 = -1.0e30f, best_2 = -1.0e30f, best_3 = -1.0e30f;
    #pragma unroll 4
    for (int i = 0; i < 16; ++i) {
        const int chunk = wv * 16 + i;
        const unsigned short* cb = ebf + (size_t)chunk * 1024;
        short8 a0 = *(const short8*)(cb + lane * 8);
        short8 a1 = *(const short8*)(cb + 512 + lane * 8);
        f32x4 acc;
#define SCR1(B0, B1, BEST)                                                   \
        acc = (f32x4){0.0f, 0.0f, 0.0f, 0.0f};                               \
        acc = MFMA16(a0, B0, acc);                                           \
        acc = MFMA16(a1, B1, acc);                                           \
        BEST = fmaxf(BEST, fmaxf(fmaxf(acc[0], acc[1]), fmaxf(acc[2], acc[3])));
        SCR1(b0_0, b1_0, best_0)
        SCR1(b0_1, b1_1, best_1)
        SCR1(b0_2, b1_2, best_2)
        SCR1(b0_3, b1_3, best_3)
#undef SCR1
    }
    {
        float v;
#define WMAX(BEST, G)                                                        \
        v = BEST;                                                            \
        v = fmaxf(v, __shfl_xor(v, 16, 64));                                 \
        v = fmaxf(v, __shfl_xor(v, 32, 64));                                 \
        if (lane < 16) s_wbest[wv * 64 + (G) * 16 + lane] = v;
        WMAX(best_0, 0) WMAX(best_1, 1) WMAX(best_2, 2) WMAX(best_3, 3)
#undef WMAX
    }
    __syncthreads();

    // ---- phase 5: threshold = cross-wave max - DELTA ----
    if (tid < 64) {
        float m0 = fmaxf(fmaxf(s_wbest[tid], s_wbest[64 + tid]),
                         fmaxf(s_wbest[128 + tid], s_wbest[192 + tid]));
        s_thr[tid] = m0 - DELTA;
    }
    __syncthreads();

    // ---- phase 6: screen pass 2 — collect candidates >= thr ----
    {
        const float thr_0 = s_thr[ 0 + col];
        const float thr_1 = s_thr[16 + col];
        const float thr_2 = s_thr[32 + col];
        const float thr_3 = s_thr[48 + col];
        #pragma unroll 4
        for (int i = 0; i < 16; ++i) {
            const int chunk = wv * 16 + i;
            const unsigned short* cb = ebf + (size_t)chunk * 1024;
            short8 a0 = *(const short8*)(cb + lane * 8);
            short8 a1 = *(const short8*)(cb + 512 + lane * 8);
            f32x4 acc;
#define SCR2(B0, B1, THR, G)                                                 \
            acc = (f32x4){0.0f, 0.0f, 0.0f, 0.0f};                           \
            acc = MFMA16(a0, B0, acc);                                       \
            acc = MFMA16(a1, B1, acc);                                       \
            _Pragma("unroll")                                                \
            for (int r = 0; r < 4; ++r)                                      \
                if (acc[r] >= THR) {                                         \
                    int tok = (G) * 16 + col;                                \
                    int pos = atomicAdd(&s_cnt[tok], 1);                     \
                    if (pos < CAP) s_cand[tok * CAP + pos] =                 \
                        chunk * 16 + (lane >> 4) * 4 + r;                    \
                }
            SCR2(b0_0, b1_0, thr_0, 0)
            SCR2(b0_1, b1_1, thr_1, 1)
            SCR2(b0_2, b1_2, thr_2, 2)
            SCR2(b0_3, b1_3, thr_3, 3)
#undef SCR2
        }
    }
    __syncthreads();

    // ---- phase 7: exact rescue (4 threads per token), LDS-resident x_rot ----
    {
        const int t = tid >> 2, jj = tid & 3;
        const float* xrow = &s_xr[t][0];
        const float xxt = s_xx[t];
        const int cnt = s_cnt[t];
        float bd = 3.402823466e38f; int bc = 1 << 30;
        if (cnt <= CAP) {
            for (int k = jj; k < cnt; k += 4) {
                int c = s_cand[t * CAP + k];
                float m = chain_m(E + (size_t)c * 64, xrow);
                float d1 = xxt + ee_g[c];          // fl(xx+ee)
                float dist = d1 - 2.0f * m;        // fl(.. - 2m), contract off
                if (dist < bd || (dist == bd && c < bc)) { bd = dist; bc = c; }
            }
        } else {                                   // overflow: exact full scan
            for (int c = jj; c < 1024; c += 4) {
                float m = chain_m(E + (size_t)c * 64, xrow);
                float d1 = xxt + ee_g[c];
                float dist = d1 - 2.0f * m;
                if (dist < bd || (dist == bd && c < bc)) { bd = dist; bc = c; }
            }
        }
        #pragma unroll
        for (int mk = 1; mk < 4; mk <<= 1) {
            float od = __shfl_xor(bd, mk, 64);
            int   oc = __shfl_xor(bc, mk, 64);
            if (od < bd || (od == bd && oc < bc)) { bd = od; bc = oc; }
        }
        const int ix = bc;
        if (jj == 0) {
            s_idx[t] = ix;
            out_idx[brow * 64 + t] = (float)ix;
            unsafeAtomicAdd(&counts[ix], 1.0f);
        }
        float* dst = dw + (size_t)ix * 64 + jj * 16;
        #pragma unroll
        for (int k = 0; k < 4; ++k) {
            float4 v = *(const float4*)&s_xr[t][jj * 16 + 4 * k];
            unsafeAtomicAdd(dst + 4 * k + 0, v.x);
            unsafeAtomicAdd(dst + 4 * k + 1, v.y);
            unsafeAtomicAdd(dst + 4 * k + 2, v.z);
            unsafeAtomicAdd(dst + 4 * k + 3, v.w);
        }
    }
    __syncthreads();   // rescue done -> s_cand/s_wbest/s_thr dead; s_q reusable

    // ---- phase 8: gather quantized rows into s_q[t][d] ----
    {
        const int w = tid >> 2, p = (tid & 3) * 16;
        const int ix = s_idx[w];
        const float* erow = E + (size_t)ix * 64 + p;
        #pragma unroll
        for (int k = 0; k < 4; ++k)
            *(float4*)&s_q[w][p + 4 * k] = *(const float4*)(erow + 4 * k);
    }
    __syncthreads();

    // ---- phase 9: straight-through output + mse ----
    float mse = 0.0f;
    #pragma unroll
    for (int i = 0; i < 4; ++i) {
        int fid = i * 256 + tid;                   // 0..1023 float4s
        int d = fid >> 4, t4 = (fid & 15) * 4;
        float4 xv = *(const float4*)(x + xbase + (size_t)d * 4096 + t4);
        float q0 = s_q[t4 + 0][d], q1 = s_q[t4 + 1][d];
        float q2 = s_q[t4 + 2][d], q3 = s_q[t4 + 3][d];
        float4 o;
        o.x = xv.x + (q0 - xv.x);
        o.y = xv.y + (q1 - xv.y);
        o.z = xv.z + (q2 - xv.z);
        o.w = xv.w + (q3 - xv.w);
        float dx = q0 - xv.x, dy = q1 - xv.y, dz = q2 - xv.z, dv = q3 - xv.w;
        mse = fmaf(dx, dx, mse); mse = fmaf(dy, dy, mse);
        mse = fmaf(dz, dz, mse); mse = fmaf(dv, dv, mse);
        *(float4*)(out_q + xbase + (size_t)d * 4096 + t4) = o;
    }
    #pragma unroll
    for (int off = 32; off > 0; off >>= 1) mse += __shfl_down(mse, off, 64);
    if ((tid & 63) == 0) s_red[tid >> 6] = mse;
    __syncthreads();
    if (tid == 0)
        unsafeAtomicAdd(mse_acc, s_red[0] + s_red[1] + s_red[2] + s_red[3]);
}

// 17 blocks x 256: blocks 0..15 -> EMA/embedding update; block 16 -> loss + new_cs.
__global__ __launch_bounds__(256) void vq_final_kernel(
    const float* __restrict__ ema_cs, const float* __restrict__ ema_w,
    const float* __restrict__ ws, float* __restrict__ out)
{
    __shared__ float s_red[8];
    __shared__ float s_inv[64];
    const int t = threadIdx.x;
    const int bid = blockIdx.x;
    const float* counts = ws + 1024;
    const float* dw     = ws + 2048;

    float part = 0.0f;
    #pragma unroll
    for (int k = 0; k < 4; ++k) {
        int c = k * 256 + t;
        part += ema_cs[c] * 0.99f + 0.01f * counts[c];
    }
    #pragma unroll
    for (int off = 32; off > 0; off >>= 1) part += __shfl_down(part, off, 64);
    if ((t & 63) == 0) s_red[t >> 6] = part;
    __syncthreads();
    const float n_tot = s_red[0] + s_red[1] + s_red[2] + s_red[3];
    const float denom = n_tot + 1024.0f * 1e-5f;

    if (bid < 16) {
        const int base_code = bid * 64;
        if (t < 64) {
            int code = base_code + t;
            float ncs = ema_cs[code] * 0.99f + 0.01f * counts[code];
            float ncs_s = (ncs + 1e-5f) / denom * n_tot;
            s_inv[t] = 1.0f / ncs_s;
        }
        __syncthreads();
        float* out_emb  = out + 4259841;
        float* out_emaw = out + 4326401;
        const int base_e = base_code * 64;
        #pragma unroll
        for (int k = 0; k < 16; ++k) {
            int el = k * 256 + t;
            int e  = base_e + el;
            float nw = ema_w[e] * 0.99f + 0.01f * dw[e];
            out_emaw[e] = nw;
            out_emb[e]  = nw * s_inv[el >> 6];
        }
    } else {
        float ent_part = 0.0f;
        #pragma unroll
        for (int k = 0; k < 4; ++k) {
            int c = k * 256 + t;
            float cnt = counts[c];
            float p   = cnt * (1.0f / 65536.0f);
            ent_part += -p * logf(p + 1e-10f);
            float ncs = ema_cs[c] * 0.99f + 0.01f * cnt;
            out[4325377 + c] = (ncs + 1e-5f) / denom * n_tot;   // new_cs
        }
        __syncthreads();
        #pragma unroll
        for (int off = 32; off > 0; off >>= 1) ent_part += __shfl_down(ent_part, off, 64);
        if ((t & 63) == 0) s_red[t >> 6] = ent_part;
        __syncthreads();
        if (t == 0) {
            float ent_tot = s_red[0] + s_red[1] + s_red[2] + s_red[3];
            out[4194304] = 1.25f * (ws[67584] * (1.0f / 4194304.0f)) + ent_tot;  // loss
        }
    }
}

extern "C" void kernel_launch(void* const* d_in, const int* in_sizes, int n_in,
                              void* d_out, int out_size, void* d_ws, size_t ws_size,
                              hipStream_t stream) {
    const float* x      = (const float*)d_in[0];
    const float* E      = (const float*)d_in[1];
    const float* R      = (const float*)d_in[2];
    const float* ema_cs = (const float*)d_in[3];
    const float* ema_w  = (const float*)d_in[4];
    float* out = (float*)d_out;
    float* ws  = (float*)d_ws;

    hipLaunchKernelGGL(vq_init_kernel,  dim3(256),  dim3(256), 0, stream, E, ws);
    hipLaunchKernelGGL(vq_main_kernel,  dim3(1024), dim3(256), 0, stream, x, E, R, ws, out);
    hipLaunchKernelGGL(vq_final_kernel, dim3(17),   dim3(256), 0, stream, ema_cs, ema_w, ws, out);
}

// Round 10
// 453.080 us; speedup vs baseline: 1.5081x; 1.5081x over previous
//
#include <hip/hip_runtime.h>
#include <cmath>

using short8 = __attribute__((ext_vector_type(8))) short;
using f32x4  = __attribute__((ext_vector_type(4))) float;

// Screen threshold: winner needs m_c >= m_best - [grid window/2 (~5e-4) +
// 2x bf16 screen err (~4.8e-4 @6sigma) + ee neglect (~2e-5)] ~= 1e-3.
// 4e-3 = 4x margin. (0.02 was ~0.55 sigma of the score spread -> every
// token overflowed CAP and took the full-scan fallback; that was round 6-8's
// 588us.) Expected candidates/token ~= 1.3.
#define DELTA 0.004f
#define CAP   16

// d_ws layout (floats):
//   [0      .. 1024)   ee[k] = numpy-pairwise sum of E[k][:]^2  (f32)
//   [1024   .. 2048)   counts[k]
//   [2048   .. 67584)  dw[k][d]  (1024*64)
//   [67584]            mse accumulator
//   [69632  .. 102400) E_bf swizzled: A-fragment order (chunk-major, lane-contig)
//
// d_out layout (floats, reference return order):
//   [0 .. 4194304) quant | [4194304] loss | [4194305 .. 4259841) idx |
//   [4259841 .. 4325377) new_embedding | [4325377..4326401) new_cs |
//   [4326401 .. 4391937) new_ema_w

__device__ __forceinline__ unsigned short f2bf(float f) {
    unsigned u = __builtin_bit_cast(unsigned, f);
    return (unsigned short)((u + 0x7FFFu + ((u >> 16) & 1u)) >> 16);
}

__global__ __launch_bounds__(256) void vq_init_kernel(const float* __restrict__ E,
                                                      float* __restrict__ ws) {
    #pragma clang fp contract(off)
    int g = blockIdx.x * 256 + threadIdx.x;        // 256 blocks -> g in [0,65536)
    ws[2048 + g] = 0.0f;                           // zero dw
    {   // E -> bf16, swizzled into MFMA A-frag order:
        // code c, dim d: kh=d>>5, kq=(d&31)>>3, j=d&7, lane=(kq<<4)|(c&15)
        // flat = (((c>>4)*2 + kh)*64 + lane)*8 + j
        int c = g >> 6, d = g & 63;
        int kh = d >> 5, kq = (d & 31) >> 3, j = d & 7;
        int lane = (kq << 4) | (c & 15);
        int flat = (((c >> 4) * 2 + kh) * 64 + lane) * 8 + j;
        ((unsigned short*)(ws + 69632))[flat] = f2bf(E[g]);
    }
    if (g < 1024) {
        ws[1024 + g] = 0.0f;                       // zero counts
        const float* e = E + g * 64;
        float r[8];                                // numpy pairwise, n=64
        #pragma unroll
        for (int j = 0; j < 8; ++j) r[j] = e[j] * e[j];
        #pragma unroll
        for (int t = 1; t < 8; ++t)
            #pragma unroll
            for (int j = 0; j < 8; ++j) {
                float sq = e[8 * t + j] * e[8 * t + j];
                r[j] = r[j] + sq;
            }
        ws[g] = ((r[0] + r[1]) + (r[2] + r[3])) + ((r[4] + r[5]) + (r[6] + r[7]));
    }
    if (g == 0) ws[67584] = 0.0f;                  // mse
}

// Streaming exact dot: d-ascending single FMA chain (bit-exact), ~12 live regs.
__device__ __forceinline__ float chain_m(const float* __restrict__ erow,
                                         const float* __restrict__ xrow) {
    #pragma clang fp contract(off)
    float m = 0.0f;
    #pragma unroll
    for (int k = 0; k < 16; ++k) {
        float4 e  = *(const float4*)(erow + 4 * k);
        float4 xv = *(const float4*)(xrow + 4 * k);
        m = fmaf(xv.x, e.x, m);
        m = fmaf(xv.y, e.y, m);
        m = fmaf(xv.z, e.z, m);
        m = fmaf(xv.w, e.w, m);
    }
    return m;
}

// bf16-pack 8 consecutive floats; returns by value (registers, not scratch).
__device__ __forceinline__ short8 pack_bf8(const float* __restrict__ xr) {
    float f0 = xr[0], f1 = xr[1], f2 = xr[2], f3 = xr[3];
    float f4 = xr[4], f5 = xr[5], f6 = xr[6], f7 = xr[7];
    short8 r;
    r[0] = (short)f2bf(f0); r[1] = (short)f2bf(f1);
    r[2] = (short)f2bf(f2); r[3] = (short)f2bf(f3);
    r[4] = (short)f2bf(f4); r[5] = (short)f2bf(f5);
    r[6] = (short)f2bf(f6); r[7] = (short)f2bf(f7);
    return r;
}

#define MFMA16(a, b, c) __builtin_amdgcn_mfma_f32_16x16x32_bf16(a, b, c, 0, 0, 0)

__global__ __launch_bounds__(256, 2) void vq_main_kernel(
    const float* __restrict__ x, const float* __restrict__ E,
    const float* __restrict__ R, float* __restrict__ ws, float* __restrict__ out)
{
    #pragma clang fp contract(off)
    __shared__ float s_xr[64][68];     // x_rot f32, exact reference bits
    __shared__ float s_q [64][68];     // phase A: s_cand/s_wbest/s_thr; phase B: quant rows
    __shared__ float s_xx[64];
    __shared__ int   s_idx[64];
    __shared__ int   s_cnt[64];
    __shared__ float s_red[8];

    int*   s_cand  = (int*)&s_q[0][0];            // [64][CAP] ints   (floats 0..1023)
    float* s_wbest = &s_q[0][0] + 1024;           // [4][64]          (floats 1024..1279)
    float* s_thr   = &s_q[0][0] + 1280;           // [64]             (floats 1280..1343)

    const int tid  = threadIdx.x;
    const int brow = blockIdx.x;       // b*64 + h
    const int b = brow >> 6, h = brow & 63;

    const float* ee_g  = ws;
    float* counts  = ws + 1024;
    float* dw      = ws + 2048;
    float* mse_acc = ws + 67584;
    const unsigned short* ebf = (const unsigned short*)(ws + 69632);
    float* out_q   = out;
    float* out_idx = out + 4194305;

    const size_t xbase = (size_t)b * 262144 + (size_t)h * 64;

    // ---- phase 1: rotate from global, exact d-ascending f32 FMA chain ----
    {
        const int tc = tid >> 4, cg = tid & 15;    // tokens 4tc..4tc+3, j 4cg..4cg+3
        float acc[4][4] = {};
        const float* xp = x + xbase + 4 * tc;
        const float* rp = R + 4 * cg;
        #pragma unroll 8
        for (int d = 0; d < 64; ++d) {
            float4 xv = *(const float4*)(xp + (size_t)d * 4096);
            float4 rv = *(const float4*)(rp + d * 64);
            float xa[4] = {xv.x, xv.y, xv.z, xv.w};
            float ra[4] = {rv.x, rv.y, rv.z, rv.w};
            #pragma unroll
            for (int i = 0; i < 4; ++i)
                #pragma unroll
                for (int jj = 0; jj < 4; ++jj)
                    acc[i][jj] = fmaf(xa[i], ra[jj], acc[i][jj]);
        }
        #pragma unroll
        for (int i = 0; i < 4; ++i)
            *(float4*)&s_xr[4 * tc + i][4 * cg] =
                make_float4(acc[i][0], acc[i][1], acc[i][2], acc[i][3]);
    }
    __syncthreads();

    // ---- phase 2: xx (numpy pairwise, exact) + counters ----
    if (tid < 64) {
        const int w = tid;
        float r[8];
        #pragma unroll
        for (int j = 0; j < 8; ++j) { float u = s_xr[w][j]; r[j] = u * u; }
        #pragma unroll
        for (int t = 1; t < 8; ++t)
            #pragma unroll
            for (int j = 0; j < 8; ++j) {
                float u = s_xr[w][8 * t + j];
                float sq = u * u;
                r[j] = r[j] + sq;
            }
        s_xx[w] = ((r[0] + r[1]) + (r[2] + r[3])) + ((r[4] + r[5]) + (r[6] + r[7]));
        s_cnt[w] = 0;
    }
    __syncthreads();

    // ---- phase 3: named b-frags (bf16) for the 4 token groups ----
    const int lane = tid & 63, wv = tid >> 6;
    const int col  = lane & 15;
    const int kb   = (lane >> 4) * 8;
    const short8 b0_0 = pack_bf8(&s_xr[ 0 + col][kb]);
    const short8 b1_0 = pack_bf8(&s_xr[ 0 + col][kb + 32]);
    const short8 b0_1 = pack_bf8(&s_xr[16 + col][kb]);
    const short8 b1_1 = pack_bf8(&s_xr[16 + col][kb + 32]);
    const short8 b0_2 = pack_bf8(&s_xr[32 + col][kb]);
    const short8 b1_2 = pack_bf8(&s_xr[32 + col][kb + 32]);
    const short8 b0_3 = pack_bf8(&s_xr[48 + col][kb]);
    const short8 b1_3 = pack_bf8(&s_xr[48 + col][kb + 32]);

    // ---- phase 4: screen pass 1 — per-token max over this wave's 256 codes ----
    float best_0 = -1.0e30f, best_1 = -1.0e30f, best_2 = -1.0e30f, best_3 = -1.0e30f;
    #pragma unroll 4
    for (int i = 0; i < 16; ++i) {
        const int chunk = wv * 16 + i;
        const unsigned short* cb = ebf + (size_t)chunk * 1024;
        short8 a0 = *(const short8*)(cb + lane * 8);
        short8 a1 = *(const short8*)(cb + 512 + lane * 8);
        f32x4 acc;
#define SCR1(B0, B1, BEST)                                                   \
        acc = (f32x4){0.0f, 0.0f, 0.0f, 0.0f};                               \
        acc = MFMA16(a0, B0, acc);                                           \
        acc = MFMA16(a1, B1, acc);                                           \
        BEST = fmaxf(BEST, fmaxf(fmaxf(acc[0], acc[1]), fmaxf(acc[2], acc[3])));
        SCR1(b0_0, b1_0, best_0)
        SCR1(b0_1, b1_1, best_1)
        SCR1(b0_2, b1_2, best_2)
        SCR1(b0_3, b1_3, best_3)
#undef SCR1
    }
    {
        float v;
#define WMAX(BEST, G)                                                        \
        v = BEST;                                                            \
        v = fmaxf(v, __shfl_xor(v, 16, 64));                                 \
        v = fmaxf(v, __shfl_xor(v, 32, 64));                                 \
        if (lane < 16) s_wbest[wv * 64 + (G) * 16 + lane] = v;
        WMAX(best_0, 0) WMAX(best_1, 1) WMAX(best_2, 2) WMAX(best_3, 3)
#undef WMAX
    }
    __syncthreads();

    // ---- phase 5: threshold = cross-wave max - DELTA ----
    if (tid < 64) {
        float m0 = fmaxf(fmaxf(s_wbest[tid], s_wbest[64 + tid]),
                         fmaxf(s_wbest[128 + tid], s_wbest[192 + tid]));
        s_thr[tid] = m0 - DELTA;
    }
    __syncthreads();

    // ---- phase 6: screen pass 2 — collect candidates >= thr ----
    {
        const float thr_0 = s_thr[ 0 + col];
        const float thr_1 = s_thr[16 + col];
        const float thr_2 = s_thr[32 + col];
        const float thr_3 = s_thr[48 + col];
        #pragma unroll 4
        for (int i = 0; i < 16; ++i) {
            const int chunk = wv * 16 + i;
            const unsigned short* cb = ebf + (size_t)chunk * 1024;
            short8 a0 = *(const short8*)(cb + lane * 8);
            short8 a1 = *(const short8*)(cb + 512 + lane * 8);
            f32x4 acc;
#define SCR2(B0, B1, THR, G)                                                 \
            acc = (f32x4){0.0f, 0.0f, 0.0f, 0.0f};                           \
            acc = MFMA16(a0, B0, acc);                                       \
            acc = MFMA16(a1, B1, acc);                                       \
            _Pragma("unroll")                                                \
            for (int r = 0; r < 4; ++r)                                      \
                if (acc[r] >= THR) {                                         \
                    int tok = (G) * 16 + col;                                \
                    int pos = atomicAdd(&s_cnt[tok], 1);                     \
                    if (pos < CAP) s_cand[tok * CAP + pos] =                 \
                        chunk * 16 + (lane >> 4) * 4 + r;                    \
                }
            SCR2(b0_0, b1_0, thr_0, 0)
            SCR2(b0_1, b1_1, thr_1, 1)
            SCR2(b0_2, b1_2, thr_2, 2)
            SCR2(b0_3, b1_3, thr_3, 3)
#undef SCR2
        }
    }
    __syncthreads();

    // ---- phase 7: exact rescue (4 threads per token), LDS-resident x_rot ----
    {
        const int t = tid >> 2, jj = tid & 3;
        const float* xrow = &s_xr[t][0];
        const float xxt = s_xx[t];
        const int cnt = s_cnt[t];
        float bd = 3.402823466e38f; int bc = 1 << 30;
        if (cnt <= CAP) {
            for (int k = jj; k < cnt; k += 4) {
                int c = s_cand[t * CAP + k];
                float m = chain_m(E + (size_t)c * 64, xrow);
                float d1 = xxt + ee_g[c];          // fl(xx+ee)
                float dist = d1 - 2.0f * m;        // fl(.. - 2m), contract off
                if (dist < bd || (dist == bd && c < bc)) { bd = dist; bc = c; }
            }
        } else {                                   // overflow: exact full scan
            for (int c = jj; c < 1024; c += 4) {
                float m = chain_m(E + (size_t)c * 64, xrow);
                float d1 = xxt + ee_g[c];
                float dist = d1 - 2.0f * m;
                if (dist < bd || (dist == bd && c < bc)) { bd = dist; bc = c; }
            }
        }
        #pragma unroll
        for (int mk = 1; mk < 4; mk <<= 1) {
            float od = __shfl_xor(bd, mk, 64);
            int   oc = __shfl_xor(bc, mk, 64);
            if (od < bd || (od == bd && oc < bc)) { bd = od; bc = oc; }
        }
        const int ix = bc;
        if (jj == 0) {
            s_idx[t] = ix;
            out_idx[brow * 64 + t] = (float)ix;
            unsafeAtomicAdd(&counts[ix], 1.0f);
        }
        float* dst = dw + (size_t)ix * 64 + jj * 16;
        #pragma unroll
        for (int k = 0; k < 4; ++k) {
            float4 v = *(const float4*)&s_xr[t][jj * 16 + 4 * k];
            unsafeAtomicAdd(dst + 4 * k + 0, v.x);
            unsafeAtomicAdd(dst + 4 * k + 1, v.y);
            unsafeAtomicAdd(dst + 4 * k + 2, v.z);
            unsafeAtomicAdd(dst + 4 * k + 3, v.w);
        }
    }
    __syncthreads();   // rescue done -> s_cand/s_wbest/s_thr dead; s_q reusable

    // ---- phase 8: gather quantized rows into s_q[t][d] ----
    {
        const int w = tid >> 2, p = (tid & 3) * 16;
        const int ix = s_idx[w];
        const float* erow = E + (size_t)ix * 64 + p;
        #pragma unroll
        for (int k = 0; k < 4; ++k)
            *(float4*)&s_q[w][p + 4 * k] = *(const float4*)(erow + 4 * k);
    }
    __syncthreads();

    // ---- phase 9: straight-through output + mse ----
    float mse = 0.0f;
    #pragma unroll
    for (int i = 0; i < 4; ++i) {
        int fid = i * 256 + tid;                   // 0..1023 float4s
        int d = fid >> 4, t4 = (fid & 15) * 4;
        float4 xv = *(const float4*)(x + xbase + (size_t)d * 4096 + t4);
        float q0 = s_q[t4 + 0][d], q1 = s_q[t4 + 1][d];
        float q2 = s_q[t4 + 2][d], q3 = s_q[t4 + 3][d];
        float4 o;
        o.x = xv.x + (q0 - xv.x);
        o.y = xv.y + (q1 - xv.y);
        o.z = xv.z + (q2 - xv.z);
        o.w = xv.w + (q3 - xv.w);
        float dx = q0 - xv.x, dy = q1 - xv.y, dz = q2 - xv.z, dv = q3 - xv.w;
        mse = fmaf(dx, dx, mse); mse = fmaf(dy, dy, mse);
        mse = fmaf(dz, dz, mse); mse = fmaf(dv, dv, mse);
        *(float4*)(out_q + xbase + (size_t)d * 4096 + t4) = o;
    }
    #pragma unroll
    for (int off = 32; off > 0; off >>= 1) mse += __shfl_down(mse, off, 64);
    if ((tid & 63) == 0) s_red[tid >> 6] = mse;
    __syncthreads();
    if (tid == 0)
        unsafeAtomicAdd(mse_acc, s_red[0] + s_red[1] + s_red[2] + s_red[3]);
}

// 17 blocks x 256: blocks 0..15 -> EMA/embedding update; block 16 -> loss + new_cs.
__global__ __launch_bounds__(256) void vq_final_kernel(
    const float* __restrict__ ema_cs, const float* __restrict__ ema_w,
    const float* __restrict__ ws, float* __restrict__ out)
{
    __shared__ float s_red[8];
    __shared__ float s_inv[64];
    const int t = threadIdx.x;
    const int bid = blockIdx.x;
    const float* counts = ws + 1024;
    const float* dw     = ws + 2048;

    float part = 0.0f;
    #pragma unroll
    for (int k = 0; k < 4; ++k) {
        int c = k * 256 + t;
        part += ema_cs[c] * 0.99f + 0.01f * counts[c];
    }
    #pragma unroll
    for (int off = 32; off > 0; off >>= 1) part += __shfl_down(part, off, 64);
    if ((t & 63) == 0) s_red[t >> 6] = part;
    __syncthreads();
    const float n_tot = s_red[0] + s_red[1] + s_red[2] + s_red[3];
    const float denom = n_tot + 1024.0f * 1e-5f;

    if (bid < 16) {
        const int base_code = bid * 64;
        if (t < 64) {
            int code = base_code + t;
            float ncs = ema_cs[code] * 0.99f + 0.01f * counts[code];
            float ncs_s = (ncs + 1e-5f) / denom * n_tot;
            s_inv[t] = 1.0f / ncs_s;
        }
        __syncthreads();
        float* out_emb  = out + 4259841;
        float* out_emaw = out + 4326401;
        const int base_e = base_code * 64;
        #pragma unroll
        for (int k = 0; k < 16; ++k) {
            int el = k * 256 + t;
            int e  = base_e + el;
            float nw = ema_w[e] * 0.99f + 0.01f * dw[e];
            out_emaw[e] = nw;
            out_emb[e]  = nw * s_inv[el >> 6];
        }
    } else {
        float ent_part = 0.0f;
        #pragma unroll
        for (int k = 0; k < 4; ++k) {
            int c = k * 256 + t;
            float cnt = counts[c];
            float p   = cnt * (1.0f / 65536.0f);
            ent_part += -p * logf(p + 1e-10f);
            float ncs = ema_cs[c] * 0.99f + 0.01f * cnt;
            out[4325377 + c] = (ncs + 1e-5f) / denom * n_tot;   // new_cs
        }
        __syncthreads();
        #pragma unroll
        for (int off = 32; off > 0; off >>= 1) ent_part += __shfl_down(ent_part, off, 64);
        if ((t & 63) == 0) s_red[t >> 6] = ent_part;
        __syncthreads();
        if (t == 0) {
            float ent_tot = s_red[0] + s_red[1] + s_red[2] + s_red[3];
            out[4194304] = 1.25f * (ws[67584] * (1.0f / 4194304.0f)) + ent_tot;  // loss
        }
    }
}

extern "C" void kernel_launch(void* const* d_in, const int* in_sizes, int n_in,
                              void* d_out, int out_size, void* d_ws, size_t ws_size,
                              hipStream_t stream) {
    const float* x      = (const float*)d_in[0];
    const float* E      = (const float*)d_in[1];
    const float* R      = (const float*)d_in[2];
    const float* ema_cs = (const float*)d_in[3];
    const float* ema_w  = (const float*)d_in[4];
    float* out = (float*)d_out;
    float* ws  = (float*)d_ws;

    hipLaunchKernelGGL(vq_init_kernel,  dim3(256),  dim3(256), 0, stream, E, ws);
    hipLaunchKernelGGL(vq_main_kernel,  dim3(1024), dim3(256), 0, stream, x, E, R, ws, out);
    hipLaunchKernelGGL(vq_final_kernel, dim3(17),   dim3(256), 0, stream, ema_cs, ema_w, ws, out);
}